// Round 3
// baseline (567.277 us; speedup 1.0000x reference)
//
#include <hip/hip_runtime.h>

// Problem constants
//   B=2, LQ=LK=2048, D=1024, H=16, DK=DV=64
// Inputs (float32 unless noted):
//   0 PE_states [2,2048,1024]   1 global_state [2,2048,1024]
//   2 PE_statements [..]        3 PE_operators [..]
//   4 PE_solution_scores [2,2048]  5 mask int32 [2,2048,2048]
//   6 w_q [1024,1024] 7 w_k 8 w_v 9 w_fc  10 ln_gamma [1024] 11 ln_beta [1024]
// Output: statement_pred ++ operator_pred, each [2,2048,1024] float32
// (reference output dtype is f32; the harness's bf16-grade threshold reflects
//  comparison tolerance for bf16-internal kernels, not storage).

typedef unsigned short u16;
typedef unsigned int   u32;
typedef unsigned long long u64;

typedef __attribute__((ext_vector_type(8))) short frag_ab;   // 8 bf16 (4 VGPRs)
typedef __attribute__((ext_vector_type(4))) float frag_cd;   // 4 f32
typedef __attribute__((ext_vector_type(8))) unsigned short u16x8;

__device__ __forceinline__ u16 f2bf(float f) {
    u32 x = __builtin_bit_cast(u32, f);
    u32 r = (x + 0x7fffu + ((x >> 16) & 1u)) >> 16;   // RNE
    return (u16)r;
}

#define LSTR 72   // padded LDS row stride in u16 (144 B -> <=2-way bank aliasing on frag reads)

// ---------------- weight transpose + downcast: out[n][k] = bf16(in[k][n]), 1024x1024 --------
__global__ __launch_bounds__(256) void transpose_kernel(
    const float* __restrict__ in, u16* __restrict__ out, int rows, int cols)
{
    __shared__ u16 tile[32][33];
    int bx = blockIdx.x * 32;   // col of in
    int by = blockIdx.y * 32;   // row of in
    int tx = threadIdx.x & 31, ty = threadIdx.x >> 5;
    for (int i = 0; i < 32; i += 8)
        tile[ty + i][tx] = f2bf(in[(size_t)(by + ty + i) * cols + bx + tx]);
    __syncthreads();
    for (int i = 0; i < 32; i += 8)
        out[(size_t)(bx + ty + i) * rows + by + tx] = tile[tx][ty + i];
}

// ---------------- pack mask to bitmask: bits[(b*2048+q)*32 + kt] bit j = mask!=0 ------------
__global__ __launch_bounds__(256) void pack_mask_kernel(
    const int* __restrict__ mask, u64* __restrict__ bits)
{
    long long gid = (long long)blockIdx.x * 256 + threadIdx.x;
    int v = mask[gid];
    u64 bl = __ballot(v != 0);
    if ((threadIdx.x & 63) == 0) bits[gid >> 6] = bl;
}

// ---------------- GEMM: C[M,N] = A[M,K] @ BT[N,K]^T --------------------------------------
// A is f32 (projections) or bf16 (fc); BT always bf16; out bf16 or f32(+f32 resid)
template<bool F32OUT, bool AF32>
__global__ __launch_bounds__(256) void gemm_kernel(
    const void* __restrict__ Av, const u16* __restrict__ BT,
    u16* __restrict__ Cb, float* __restrict__ Cf, const float* __restrict__ resid,
    int M, int N, int K)
{
    __shared__ alignas(16) u16 Asm[64][LSTR];
    __shared__ alignas(16) u16 Bsm[64][LSTR];
    const int tid = threadIdx.x;
    const int wave = tid >> 6, lane = tid & 63;
    const int ln15 = lane & 15, quad = lane >> 4;
    const int bm = blockIdx.x * 64, bn = blockIdx.y * 64;
    const int wm = (wave & 1) * 32, wn = (wave >> 1) * 32;
    frag_cd acc[2][2] = {};
    const int lr = tid >> 3;         // 0..31
    const int lc = (tid & 7) * 8;    // 0..56

    for (int k0 = 0; k0 < K; k0 += 64) {
        for (int i = 0; i < 2; i++) {
            int r = lr + i * 32;
            if (AF32) {
                const float* A = (const float*)Av;
                const float* ap = &A[(size_t)(bm + r) * K + k0 + lc];
                float4 f0 = *(const float4*)ap;
                float4 f1 = *(const float4*)(ap + 4);
                u16x8 t;
                t[0] = f2bf(f0.x); t[1] = f2bf(f0.y); t[2] = f2bf(f0.z); t[3] = f2bf(f0.w);
                t[4] = f2bf(f1.x); t[5] = f2bf(f1.y); t[6] = f2bf(f1.z); t[7] = f2bf(f1.w);
                *(u16x8*)&Asm[r][lc] = t;
            } else {
                const u16* A = (const u16*)Av;
                *(u16x8*)&Asm[r][lc] = *(const u16x8*)&A[(size_t)(bm + r) * K + k0 + lc];
            }
            *(u16x8*)&Bsm[r][lc] = *(const u16x8*)&BT[(size_t)(bn + r) * K + k0 + lc];
        }
        __syncthreads();
        for (int ks = 0; ks < 2; ks++) {
            frag_ab a[2], b[2];
            for (int i = 0; i < 2; i++)
                a[i] = *(const frag_ab*)&Asm[wm + i * 16 + ln15][ks * 32 + quad * 8];
            for (int j = 0; j < 2; j++)
                b[j] = *(const frag_ab*)&Bsm[wn + j * 16 + ln15][ks * 32 + quad * 8];
            for (int i = 0; i < 2; i++)
                for (int j = 0; j < 2; j++)
                    acc[i][j] = __builtin_amdgcn_mfma_f32_16x16x32_bf16(a[i], b[j], acc[i][j], 0, 0, 0);
        }
        __syncthreads();
    }
    // C/D layout: col = lane&15, row = quad*4 + reg  [verified m89/m91]
    for (int i = 0; i < 2; i++) for (int j = 0; j < 2; j++) {
        int row0 = bm + wm + i * 16 + quad * 4;
        int col = bn + wn + j * 16 + ln15;
        for (int r = 0; r < 4; r++) {
            size_t off = (size_t)(row0 + r) * N + col;
            float v = acc[i][j][r];
            if (F32OUT) {
                Cf[off] = v + resid[off];
            } else {
                Cb[off] = f2bf(v);
            }
        }
    }
}

// ---------------- flash attention: one (b,h,64-q-row) block; shared P for Vs and Vo --------
__global__ __launch_bounds__(256) void flash_kernel(
    const u16* __restrict__ Q, const u16* __restrict__ Kp,
    const u16* __restrict__ Vs, const u16* __restrict__ Vo,
    const float* __restrict__ scores, const u64* __restrict__ mbits,
    u16* __restrict__ Os, u16* __restrict__ Oo)
{
    __shared__ alignas(16) u16 Ksm[64][LSTR];
    __shared__ alignas(16) u16 VsT[64][LSTR];   // [dv][key], key-block XOR-swizzled
    __shared__ alignas(16) u16 VoT[64][LSTR];
    __shared__ alignas(16) u16 Psm[64][LSTR];   // wave-private 16-row strips
    const int qt = blockIdx.x, h = blockIdx.y, b = blockIdx.z;
    const int tid = threadIdx.x;
    const int wave = tid >> 6, lane = tid & 63;
    const int ln15 = lane & 15, quad = lane >> 4;
    const int q0 = qt * 64;

    // Q fragments (A-operand): rows wave*16+ln15, dk = ks*32 + quad*8 + j
    frag_ab aq[2];
    {
        const u16* qp = &Q[(size_t)(b * 2048 + q0 + wave * 16 + ln15) * 1024 + h * 64 + quad * 8];
        aq[0] = *(const frag_ab*)qp;
        aq[1] = *(const frag_ab*)(qp + 32);
    }
    frag_cd os_[4] = {}, oo_[4] = {};
    float m_i[4], l_i[4];
    for (int r = 0; r < 4; r++) { m_i[r] = -1e30f; l_i[r] = 0.0f; }

    const int lr = tid >> 3;        // 0..31
    const int lc = (tid & 7) * 8;   // 0..56

    for (int kt = 0; kt < 32; kt++) {
        const int k0 = kt * 64;
        // stage K tile [key][dk]; V tiles transposed [dv][key'] with kb' = (key>>3)^(dv>>3)
        for (int i = 0; i < 2; i++) {
            int r = lr + i * 32;
            size_t grow = (size_t)(b * 2048 + k0 + r) * 1024 + h * 64 + lc;
            *(u16x8*)&Ksm[r][lc] = *(const u16x8*)&Kp[grow];
            u16x8 v8s = *(const u16x8*)&Vs[grow];
            u16x8 v8o = *(const u16x8*)&Vo[grow];
            int rb = r >> 3, rlo = r & 7;
            for (int j = 0; j < 8; j++) {
                int dv = lc + j;
                int kb = rb ^ (dv >> 3);
                VsT[dv][kb * 8 + rlo] = v8s[j];
                VoT[dv][kb * 8 + rlo] = v8o[j];
            }
        }
        __syncthreads();

        // S = Q K^T  (B-frag straight from row-major K: B[dk][key] = K[key][dk])
        frag_cd sacc[4] = {};
        for (int ks = 0; ks < 2; ks++)
            for (int nt = 0; nt < 4; nt++) {
                frag_ab bk = *(const frag_ab*)&Ksm[nt * 16 + ln15][ks * 32 + quad * 8];
                sacc[nt] = __builtin_amdgcn_mfma_f32_16x16x32_bf16(aq[ks], bk, sacc[nt], 0, 0, 0);
            }

        // bias + mask:  s' = (s/8 + score_k)/2 ; mask==0 -> -1e9 (matches reference semantics
        // including the all-masked-row -> uniform softmax degenerate case)
        float sc[4];
        for (int nt = 0; nt < 4; nt++)
            sc[nt] = scores[b * 2048 + k0 + nt * 16 + ln15] * 0.5f;
        u64 bits[4];
        for (int r = 0; r < 4; r++)
            bits[r] = mbits[(size_t)(b * 2048 + q0 + wave * 16 + quad * 4 + r) * 32 + kt];

        float p[4][4];
        for (int nt = 0; nt < 4; nt++)
            for (int r = 0; r < 4; r++) {
                float s = sacc[nt][r] * 0.0625f + sc[nt];
                if (!((bits[r] >> (nt * 16 + ln15)) & 1ull)) s = -1e9f;
                p[nt][r] = s;
            }

        // online softmax per row (row r lives in the 16 lanes of this quad)
        for (int r = 0; r < 4; r++) {
            float mx = fmaxf(fmaxf(p[0][r], p[1][r]), fmaxf(p[2][r], p[3][r]));
            for (int off = 1; off < 16; off <<= 1)
                mx = fmaxf(mx, __shfl_xor(mx, off, 64));
            float mnew = fmaxf(m_i[r], mx);
            float alpha = __expf(m_i[r] - mnew);
            float rs = 0.0f;
            for (int nt = 0; nt < 4; nt++) {
                float e = __expf(p[nt][r] - mnew);
                p[nt][r] = e;
                rs += e;
            }
            for (int off = 1; off < 16; off <<= 1)
                rs += __shfl_xor(rs, off, 64);
            l_i[r] = l_i[r] * alpha + rs;
            m_i[r] = mnew;
            for (int nt = 0; nt < 4; nt++) {
                os_[nt][r] *= alpha;
                oo_[nt][r] *= alpha;
            }
        }

        // P: C-layout -> LDS -> A-layout (wave-private rows; DS pipe is in-order per wave)
        for (int nt = 0; nt < 4; nt++)
            for (int r = 0; r < 4; r++)
                Psm[wave * 16 + quad * 4 + r][nt * 16 + ln15] = f2bf(p[nt][r]);

        frag_ab ap[2];
        ap[0] = *(const frag_ab*)&Psm[wave * 16 + ln15][quad * 8];
        ap[1] = *(const frag_ab*)&Psm[wave * 16 + ln15][32 + quad * 8];
        for (int ks = 0; ks < 2; ks++)
            for (int nt = 0; nt < 4; nt++) {
                int dv = nt * 16 + ln15;
                int kb = (ks * 4 + quad) ^ (dv >> 3);
                frag_ab bs = *(const frag_ab*)&VsT[dv][kb * 8];
                os_[nt] = __builtin_amdgcn_mfma_f32_16x16x32_bf16(ap[ks], bs, os_[nt], 0, 0, 0);
                frag_ab bo = *(const frag_ab*)&VoT[dv][kb * 8];
                oo_[nt] = __builtin_amdgcn_mfma_f32_16x16x32_bf16(ap[ks], bo, oo_[nt], 0, 0, 0);
            }
        __syncthreads();
    }

    for (int r = 0; r < 4; r++) {
        float inv = 1.0f / l_i[r];
        for (int nt = 0; nt < 4; nt++) {
            int row = q0 + wave * 16 + quad * 4 + r;
            int col = h * 64 + nt * 16 + ln15;
            size_t off = (size_t)(b * 2048 + row) * 1024 + col;
            Os[off] = f2bf(os_[nt][r] * inv);
            Oo[off] = f2bf(oo_[nt][r] * inv);
        }
    }
}

// ---------------- row LayerNorm (D=1024) : f32 in, f32 out ----------------
__global__ __launch_bounds__(256) void ln_kernel(
    const float* __restrict__ X, const float* __restrict__ gamma, const float* __restrict__ beta,
    float* __restrict__ out)
{
    __shared__ float red[4];
    int row = blockIdx.x;
    int tid = threadIdx.x;
    const float* x = X + (size_t)row * 1024;
    float v[4];
    float s = 0.f;
    for (int i = 0; i < 4; i++) { v[i] = x[tid + i * 256]; s += v[i]; }
    for (int off = 1; off < 64; off <<= 1) s += __shfl_xor(s, off, 64);
    int wv = tid >> 6, ln = tid & 63;
    if (ln == 0) red[wv] = s;
    __syncthreads();
    float mean = (red[0] + red[1] + red[2] + red[3]) * (1.0f / 1024.0f);
    float s2 = 0.f;
    for (int i = 0; i < 4; i++) { float d = v[i] - mean; s2 += d * d; }
    for (int off = 1; off < 64; off <<= 1) s2 += __shfl_xor(s2, off, 64);
    __syncthreads();
    if (ln == 0) red[wv] = s2;
    __syncthreads();
    float var = (red[0] + red[1] + red[2] + red[3]) * (1.0f / 1024.0f);
    float rstd = rsqrtf(var + 1e-6f);
    for (int i = 0; i < 4; i++) {
        int c = tid + i * 256;
        out[(size_t)row * 1024 + c] = (v[i] - mean) * rstd * gamma[c] + beta[c];
    }
}

extern "C" void kernel_launch(void* const* d_in, const int* in_sizes, int n_in,
                              void* d_out, int out_size, void* d_ws, size_t ws_size,
                              hipStream_t stream)
{
    const float* PE_states     = (const float*)d_in[0];
    const float* global_state  = (const float*)d_in[1];
    const float* PE_statements = (const float*)d_in[2];
    const float* PE_operators  = (const float*)d_in[3];
    const float* scores        = (const float*)d_in[4];
    const int*   mask          = (const int*)d_in[5];
    const float* w_q  = (const float*)d_in[6];
    const float* w_k  = (const float*)d_in[7];
    const float* w_v  = (const float*)d_in[8];
    const float* w_fc = (const float*)d_in[9];
    const float* gamma = (const float*)d_in[10];
    const float* beta  = (const float*)d_in[11];
    float* out = (float*)d_out;

    // workspace layout (57 MB peak)
    char* ws = (char*)d_ws;
    const size_t MB = 1u << 20;
    u16* wqT  = (u16*)(ws + 0 * MB);    // 2 MB each, bf16 transposed weights
    u16* wkT  = (u16*)(ws + 2 * MB);
    u16* wvT  = (u16*)(ws + 4 * MB);
    u16* wfcT = (u16*)(ws + 6 * MB);
    u16* Qb   = (u16*)(ws + 8 * MB);    // 8 MB each [4096][1024] bf16
    u16* Kb   = (u16*)(ws + 16 * MB);
    u16* Vsb  = (u16*)(ws + 24 * MB);
    u16* Vob  = (u16*)(ws + 32 * MB);
    u16* Osb  = (u16*)(ws + 40 * MB);
    u16* Oob  = (u16*)(ws + 48 * MB);
    u64* mbits = (u64*)(ws + 56 * MB);  // 1 MB
    float* preLN = (float*)(ws + 8 * MB);  // 16 MB f32, reuses Qb+Kb (dead after flash)

    dim3 tg(32, 32);
    transpose_kernel<<<tg, 256, 0, stream>>>(w_q, wqT, 1024, 1024);
    transpose_kernel<<<tg, 256, 0, stream>>>(w_k, wkT, 1024, 1024);
    transpose_kernel<<<tg, 256, 0, stream>>>(w_v, wvT, 1024, 1024);
    transpose_kernel<<<tg, 256, 0, stream>>>(w_fc, wfcT, 1024, 1024);

    pack_mask_kernel<<<32768, 256, 0, stream>>>(mask, mbits);

    dim3 gg(64, 16);
    gemm_kernel<false, true><<<gg, 256, 0, stream>>>(global_state, wqT, Qb, nullptr, nullptr, 4096, 1024, 1024);
    gemm_kernel<false, true><<<gg, 256, 0, stream>>>(PE_states, wkT, Kb, nullptr, nullptr, 4096, 1024, 1024);
    gemm_kernel<false, true><<<gg, 256, 0, stream>>>(PE_statements, wvT, Vsb, nullptr, nullptr, 4096, 1024, 1024);
    gemm_kernel<false, true><<<gg, 256, 0, stream>>>(PE_operators, wvT, Vob, nullptr, nullptr, 4096, 1024, 1024);

    dim3 fg(32, 16, 2);
    flash_kernel<<<fg, 256, 0, stream>>>(Qb, Kb, Vsb, Vob, scores, mbits, Osb, Oob);

    gemm_kernel<true, false><<<gg, 256, 0, stream>>>(Osb, wfcT, nullptr, preLN, global_state, 4096, 1024, 1024);
    ln_kernel<<<4096, 256, 0, stream>>>(preLN, gamma, beta, out);
    gemm_kernel<true, false><<<gg, 256, 0, stream>>>(Oob, wfcT, nullptr, preLN, global_state, 4096, 1024, 1024);
    ln_kernel<<<4096, 256, 0, stream>>>(preLN, gamma, beta, out + 4194304);
}